// Round 5
// baseline (273.291 us; speedup 1.0000x reference)
//
#include <hip/hip_runtime.h>

// GraphSAGE 3-layer forward.
// CSR build via 2-level bucketing (dst>>7 buckets of 128 nodes):
//   k_bhist -> k_bscan -> k_bucket (packed (src<<16|dst) into bucket regions)
//   -> k_csr (per-bucket per-dst scan -> off/invd/srcs).
// Feature pipeline (bf16): cast x once; per layer ONE fused kernel (R5):
//   k_layer: block = 64 nodes; phase 1 gather-mean -> LDS (XOR-swizzled, 16KB);
//            phase 2 MFMA combine (mfma_f32_16x16x32_bf16), mean from LDS,
//            h from global, weights pre-packed in fragment order.
// N=50000, E=800000, D=128, K=256. Requires N <= 65536 (16-bit edge packing).

#define D 128

typedef __attribute__((ext_vector_type(8))) short bf16x8;
typedef __attribute__((ext_vector_type(4))) float f32x4;

__device__ inline ushort f2bf(float f) {
  union { float f; unsigned u; } v; v.f = f;
  unsigned r = v.u + 0x7fffu + ((v.u >> 16) & 1u);
  return (ushort)(r >> 16);
}
__device__ inline float bf2f(ushort h) {
  union { unsigned u; float f; } v; v.u = ((unsigned)h) << 16;
  return v.f;
}

// ---- CSR stage 1: global bucket histogram (LDS-aggregated) ----
__global__ __launch_bounds__(256) void k_bhist(const int* __restrict__ dst,
                                               int* __restrict__ bhist, int E, int NB) {
  __shared__ int h[512];
  int t = threadIdx.x;
  for (int i = t; i < NB; i += 256) h[i] = 0;
  __syncthreads();
  int beg = blockIdx.x * 4096;
  int end = min(beg + 4096, E);
  for (int i = beg + t; i < end; i += 256) atomicAdd(&h[dst[i] >> 7], 1);
  __syncthreads();
  for (int i = t; i < NB; i += 256)
    if (h[i]) atomicAdd(&bhist[i], h[i]);
}

// ---- CSR stage 2: scan bucket counts -> bases; init cursors; off[N]=E ----
__global__ __launch_bounds__(512) void k_bscan(const int* __restrict__ bhist,
                                               int* __restrict__ bbase,
                                               int* __restrict__ bcur,
                                               int* __restrict__ offN, int NB) {
  __shared__ int part[512];
  int t = threadIdx.x;
  part[t] = (t < NB) ? bhist[t] : 0;
  __syncthreads();
  for (int d = 1; d < 512; d <<= 1) {
    int x = part[t];
    int a = (t >= d) ? part[t - d] : 0;
    __syncthreads();
    part[t] = x + a;
    __syncthreads();
  }
  if (t < NB) {
    int b = (t == 0) ? 0 : part[t - 1];
    bbase[t] = b;
    bcur[t] = b;
  }
  if (t == NB - 1) *offN = part[t];
}

// ---- CSR stage 3: partition edges into bucket regions (packed u32) ----
__global__ __launch_bounds__(256) void k_bucket(const int* __restrict__ src,
                                                const int* __restrict__ dst,
                                                int* __restrict__ bcur,
                                                unsigned* __restrict__ ebuf,
                                                int E, int NB) {
  __shared__ int h[512];
  __shared__ int base[512];
  int t = threadIdx.x;
  for (int i = t; i < NB; i += 256) h[i] = 0;
  __syncthreads();
  int beg = blockIdx.x * 4096;
  int end = min(beg + 4096, E);
  for (int i = beg + t; i < end; i += 256) atomicAdd(&h[dst[i] >> 7], 1);
  __syncthreads();
  for (int i = t; i < NB; i += 256) {
    int c = h[i];
    base[i] = c ? atomicAdd(&bcur[i], c) : 0;
    h[i] = 0;
  }
  __syncthreads();
  for (int i = beg + t; i < end; i += 256) {
    int d = dst[i];
    int b = d >> 7;
    int r = atomicAdd(&h[b], 1);
    ebuf[base[b] + r] = (((unsigned)src[i]) << 16) | (unsigned)d;
  }
}

// ---- CSR stage 4: per-bucket per-dst CSR (one block per bucket) ----
__global__ __launch_bounds__(256) void k_csr(const unsigned* __restrict__ ebuf,
                                             const int* __restrict__ bbase,
                                             const int* __restrict__ bhist,
                                             int* __restrict__ off,
                                             float* __restrict__ invd,
                                             int* __restrict__ srcs, int N) {
  __shared__ int dcount[128];
  __shared__ int dloc[128];
  int b = blockIdx.x;
  int t = threadIdx.x;
  int beg = bbase[b];
  int end = beg + bhist[b];
  if (t < 128) dcount[t] = 0;
  __syncthreads();
  for (int i = beg + t; i < end; i += 256) atomicAdd(&dcount[ebuf[i] & 127], 1);
  __syncthreads();
  if (t < 128) dloc[t] = dcount[t];
  __syncthreads();
  for (int d = 1; d < 128; d <<= 1) {
    int x = 0, a = 0;
    if (t < 128) {
      x = dloc[t];
      if (t >= d) a = dloc[t - d];
    }
    __syncthreads();
    if (t < 128) dloc[t] = x + a;
    __syncthreads();
  }
  if (t < 128) {
    int node = b * 128 + t;
    if (node < N) {
      int ex = beg + dloc[t] - dcount[t];
      off[node] = ex;
      int c = dcount[t];
      invd[node] = c > 0 ? 1.0f / (float)c : 0.0f;
      dcount[t] = ex;  // becomes cursor
    }
  }
  __syncthreads();
  for (int i = beg + t; i < end; i += 256) {
    unsigned p = ebuf[i];
    int slot = atomicAdd(&dcount[p & 127], 1);
    srcs[slot] = (int)(p >> 16);
  }
}

// ---- fp32 -> bf16 cast, 4 elems/thread ----
__global__ void k_cast(const float* __restrict__ x, ushort* __restrict__ xb, int total4) {
  int i = blockIdx.x * blockDim.x + threadIdx.x;
  if (i >= total4) return;
  float4 v = *reinterpret_cast<const float4*>(x + (size_t)i * 4);
  ushort4 o;
  o.x = f2bf(v.x); o.y = f2bf(v.y); o.z = f2bf(v.z); o.w = f2bf(v.w);
  *reinterpret_cast<ushort4*>(xb + (size_t)i * 4) = o;
}

// ---- pack all 3 layers' [Wl;Wr] into MFMA B-fragment order, bf16 ----
// Per layer: element idx = ((kk*8+ct)*64 + lane)*8 + j holds
//   B[kk*32+(lane>>4)*8+j][ct*16+(lane&15)]   (B = [Wl;Wr], K=256 x 128)
__global__ void k_pack3(const float* __restrict__ Wl1, const float* __restrict__ Wr1,
                        const float* __restrict__ Wl2, const float* __restrict__ Wr2,
                        const float* __restrict__ Wl3, const float* __restrict__ Wr3,
                        ushort* __restrict__ Bp) {
  int gidx = blockIdx.x * blockDim.x + threadIdx.x;  // 3*32768 total
  int layer = gidx >> 15;
  int idx = gidx & 32767;
  const float* Wl = (layer == 0) ? Wl1 : (layer == 1) ? Wl2 : Wl3;
  const float* Wr = (layer == 0) ? Wr1 : (layer == 1) ? Wr2 : Wr3;
  int kk = idx >> 12;
  int ct = (idx >> 9) & 7;
  int l  = (idx >> 3) & 63;
  int j  = idx & 7;
  int k = kk * 32 + ((l >> 4) << 3) + j;
  int col = ct * 16 + (l & 15);
  float v = (k < 128) ? Wl[k * 128 + col] : Wr[(k - 128) * 128 + col];
  Bp[gidx] = f2bf(v);
}

// ---- fused layer: gather-mean (-> LDS) + MFMA combine ----
// Block = 256 thr = 4 waves, 64 nodes. LDS mean tile 64x128 bf16 (16KB),
// stored with byte ^= ((row&7)<<4) swizzle (16B granules) -> <=2-way conflicts.
// Combine: wave w owns rows [w*16, w*16+16) of the tile.
//   A-frag: lane l holds A[row][kk*32+(l>>4)*8 + 0..7]; kk<4 from LDS(mean),
//           kk>=4 from global h row (16B load, L2-hot).
//   B-frag: pre-packed, lane loads 16B at ((kk*8+ct)*64+l)*8.
//   C/D: row=(l>>4)*4+reg, col=ct*16+(l&15)  [m89-verified layout]
template <int RELU, int FINAL>
__global__ __launch_bounds__(256) void k_layer(const ushort* __restrict__ hin,
                                               const int* __restrict__ off,
                                               const int* __restrict__ srcs,
                                               const float* __restrict__ invd,
                                               const ushort* __restrict__ Bpack,
                                               const float* __restrict__ bias,
                                               float* __restrict__ outf,
                                               ushort* __restrict__ outh, int N) {
  __shared__ ushort smean[64 * D];  // 16KB, swizzled
  int t = threadIdx.x;
  int node0 = blockIdx.x * 64;

  // --- phase 1: gather-mean, 16 lanes per node, 4 iterations of 16 nodes ---
  int sub = t & 15;
  int c = sub * 8;
#pragma unroll
  for (int it = 0; it < 4; ++it) {
    int nl = it * 16 + (t >> 4);
    int n = node0 + nl;
    float acc[8] = {0.f, 0.f, 0.f, 0.f, 0.f, 0.f, 0.f, 0.f};
    if (n < N) {
      int lo = off[n], hi = off[n + 1];
      for (int e = lo; e < hi; ++e) {
        int s = srcs[e];
        bf16x8 v = *reinterpret_cast<const bf16x8*>(hin + (size_t)s * D + c);
#pragma unroll
        for (int j = 0; j < 8; ++j) acc[j] += bf2f((ushort)v[j]);
      }
      float wgt = invd[n];
#pragma unroll
      for (int j = 0; j < 8; ++j) acc[j] *= wgt;
    }
    bf16x8 ov;
#pragma unroll
    for (int j = 0; j < 8; ++j) ov[j] = (short)f2bf(acc[j]);
    int byte = nl * 256 + ((sub * 16) ^ ((nl & 7) << 4));
    *reinterpret_cast<bf16x8*>(reinterpret_cast<char*>(smean) + byte) = ov;
  }
  __syncthreads();

  // --- phase 2: MFMA combine ---
  int l = t & 63;
  int w = t >> 6;
  int lr = l & 15;
  int kgrp = l >> 4;
  int nlrow = w * 16 + lr;        // local A row 0..63
  int arow = node0 + nlrow;
  if (arow >= N) arow = N - 1;    // clamp loads; stores guarded
  size_t abase = (size_t)arow * D;

  f32x4 acc[8];
#pragma unroll
  for (int ct = 0; ct < 8; ++ct) {
    float bv = bias[ct * 16 + lr];
    acc[ct] = (f32x4){bv, bv, bv, bv};
  }

#pragma unroll
  for (int kk = 0; kk < 8; ++kk) {
    int klocal = ((kk & 3) << 5) + (kgrp << 3);
    bf16x8 a;
    if (kk < 4) {
      int byte = nlrow * 256 + ((klocal * 2) ^ ((nlrow & 7) << 4));
      a = *reinterpret_cast<const bf16x8*>(reinterpret_cast<const char*>(smean) + byte);
    } else {
      a = *reinterpret_cast<const bf16x8*>(hin + abase + klocal);
    }
    const ushort* bb = Bpack + ((size_t)kk << 12) + ((size_t)l << 3);
#pragma unroll
    for (int ct = 0; ct < 8; ++ct) {
      bf16x8 b = *reinterpret_cast<const bf16x8*>(bb + (ct << 9));
      acc[ct] = __builtin_amdgcn_mfma_f32_16x16x32_bf16(a, b, acc[ct], 0, 0, 0);
    }
  }

#pragma unroll
  for (int ct = 0; ct < 8; ++ct) {
    int col = ct * 16 + lr;
#pragma unroll
    for (int r = 0; r < 4; ++r) {
      int rr = node0 + w * 16 + kgrp * 4 + r;
      if (rr < N) {
        float v = acc[ct][r];
        if (RELU) v = fmaxf(v, 0.f);
        if (FINAL) outf[(size_t)rr * D + col] = v;
        else outh[(size_t)rr * D + col] = f2bf(v);
      }
    }
  }
}

extern "C" void kernel_launch(void* const* d_in, const int* in_sizes, int n_in,
                              void* d_out, int out_size, void* d_ws, size_t ws_size,
                              hipStream_t stream) {
  const float* x   = (const float*)d_in[0];
  const int*   ei  = (const int*)d_in[1];
  const float* Wl1 = (const float*)d_in[2];
  const float* b1  = (const float*)d_in[3];
  const float* Wr1 = (const float*)d_in[4];
  const float* Wl2 = (const float*)d_in[5];
  const float* b2  = (const float*)d_in[6];
  const float* Wr2 = (const float*)d_in[7];
  const float* Wl3 = (const float*)d_in[8];
  const float* b3  = (const float*)d_in[9];
  const float* Wr3 = (const float*)d_in[10];
  float* out = (float*)d_out;

  int N = in_sizes[0] / D;
  int E = in_sizes[1] / 2;
  const int* srcp = ei;
  const int* dstp = ei + E;
  int NB = (N + 127) >> 7;  // 391 for N=50000

  char* p = (char*)d_ws;
  auto carve = [&](size_t bytes) {
    void* r = (void*)p;
    p += (bytes + 255) & ~(size_t)255;
    return r;
  };
  int*      bhist = (int*)carve((size_t)512 * 4);
  int*      bbase = (int*)carve((size_t)512 * 4);
  int*      bcur  = (int*)carve((size_t)512 * 4);
  int*      off   = (int*)carve((size_t)(N + 1) * 4);
  float*    invd  = (float*)carve((size_t)N * 4);
  int*      srcs  = (int*)carve((size_t)E * 4);
  unsigned* ebuf  = (unsigned*)carve((size_t)E * 4);
  ushort*   xb    = (ushort*)carve((size_t)N * D * 2);
  ushort*   h1b   = (ushort*)carve((size_t)N * D * 2);
  ushort*   h2b   = (ushort*)carve((size_t)N * D * 2);
  ushort*   Bp    = (ushort*)carve((size_t)3 * 32768 * 2);

  // --- CSR build (bucketed) ---
  hipMemsetAsync(bhist, 0, (size_t)NB * 4, stream);
  int ch_blocks = (E + 4095) / 4096;
  k_bhist<<<ch_blocks, 256, 0, stream>>>(dstp, bhist, E, NB);
  k_bscan<<<1, 512, 0, stream>>>(bhist, bbase, bcur, off + N, NB);
  k_bucket<<<ch_blocks, 256, 0, stream>>>(srcp, dstp, bcur, ebuf, E, NB);
  k_csr<<<NB, 256, 0, stream>>>(ebuf, bbase, bhist, off, invd, srcs, N);

  // --- casts + weight packing ---
  int total4 = N * D / 4;
  k_cast<<<(total4 + 255) / 256, 256, 0, stream>>>(x, xb, total4);
  k_pack3<<<3 * 32768 / 256, 256, 0, stream>>>(Wl1, Wr1, Wl2, Wr2, Wl3, Wr3, Bp);

  int layer_blocks = (N + 63) / 64;

  // --- fused layers ---
  k_layer<1, 0><<<layer_blocks, 256, 0, stream>>>(xb, off, srcs, invd, Bp, b1, nullptr, h1b, N);
  k_layer<1, 0><<<layer_blocks, 256, 0, stream>>>(h1b, off, srcs, invd, Bp + 32768, b2, nullptr, h2b, N);
  k_layer<0, 1><<<layer_blocks, 256, 0, stream>>>(h2b, off, srcs, invd, Bp + 2 * 32768, b3, out, nullptr, N);
}

// Round 6
// 199.024 us; speedup vs baseline: 1.3732x; 1.3732x over previous
//
#include <hip/hip_runtime.h>

// GraphSAGE 3-layer forward.
// CSR build via 2-level bucketing (dst>>7 buckets of 128 nodes):
//   k_bhist -> k_bscan -> k_bucket (packed (src<<16|dst) into bucket regions)
//   -> k_csr (per-bucket per-dst scan -> off/invd/srcs).
// Feature pipeline (bf16): cast x once; per layer:
//   k_gather (R6: ONE WAVE PER NODE, lane = 2 features, shfl-broadcast edge
//             indices, 4x-unrolled row reads for MLP; R5 fusion reverted --
//             it cut TLP to 3 waves/SIMD and went latency-bound)
//   k_combine (MFMA mfma_f32_16x16x32_bf16, weights pre-packed in frag order).
// N=50000, E=800000, D=128, K=256. Requires N <= 65536 (16-bit edge packing).

#define D 128

typedef __attribute__((ext_vector_type(8))) short bf16x8;
typedef __attribute__((ext_vector_type(4))) float f32x4;

__device__ inline ushort f2bf(float f) {
  union { float f; unsigned u; } v; v.f = f;
  unsigned r = v.u + 0x7fffu + ((v.u >> 16) & 1u);
  return (ushort)(r >> 16);
}
__device__ inline float bf2f(ushort h) {
  union { unsigned u; float f; } v; v.u = ((unsigned)h) << 16;
  return v.f;
}

// ---- CSR stage 1: global bucket histogram (LDS-aggregated) ----
__global__ __launch_bounds__(256) void k_bhist(const int* __restrict__ dst,
                                               int* __restrict__ bhist, int E, int NB) {
  __shared__ int h[512];
  int t = threadIdx.x;
  for (int i = t; i < NB; i += 256) h[i] = 0;
  __syncthreads();
  int beg = blockIdx.x * 4096;
  int end = min(beg + 4096, E);
  for (int i = beg + t; i < end; i += 256) atomicAdd(&h[dst[i] >> 7], 1);
  __syncthreads();
  for (int i = t; i < NB; i += 256)
    if (h[i]) atomicAdd(&bhist[i], h[i]);
}

// ---- CSR stage 2: scan bucket counts -> bases; init cursors; off[N]=E ----
__global__ __launch_bounds__(512) void k_bscan(const int* __restrict__ bhist,
                                               int* __restrict__ bbase,
                                               int* __restrict__ bcur,
                                               int* __restrict__ offN, int NB) {
  __shared__ int part[512];
  int t = threadIdx.x;
  part[t] = (t < NB) ? bhist[t] : 0;
  __syncthreads();
  for (int d = 1; d < 512; d <<= 1) {
    int x = part[t];
    int a = (t >= d) ? part[t - d] : 0;
    __syncthreads();
    part[t] = x + a;
    __syncthreads();
  }
  if (t < NB) {
    int b = (t == 0) ? 0 : part[t - 1];
    bbase[t] = b;
    bcur[t] = b;
  }
  if (t == NB - 1) *offN = part[t];
}

// ---- CSR stage 3: partition edges into bucket regions (packed u32) ----
__global__ __launch_bounds__(256) void k_bucket(const int* __restrict__ src,
                                                const int* __restrict__ dst,
                                                int* __restrict__ bcur,
                                                unsigned* __restrict__ ebuf,
                                                int E, int NB) {
  __shared__ int h[512];
  __shared__ int base[512];
  int t = threadIdx.x;
  for (int i = t; i < NB; i += 256) h[i] = 0;
  __syncthreads();
  int beg = blockIdx.x * 4096;
  int end = min(beg + 4096, E);
  for (int i = beg + t; i < end; i += 256) atomicAdd(&h[dst[i] >> 7], 1);
  __syncthreads();
  for (int i = t; i < NB; i += 256) {
    int c = h[i];
    base[i] = c ? atomicAdd(&bcur[i], c) : 0;
    h[i] = 0;
  }
  __syncthreads();
  for (int i = beg + t; i < end; i += 256) {
    int d = dst[i];
    int b = d >> 7;
    int r = atomicAdd(&h[b], 1);
    ebuf[base[b] + r] = (((unsigned)src[i]) << 16) | (unsigned)d;
  }
}

// ---- CSR stage 4: per-bucket per-dst CSR (one block per bucket) ----
__global__ __launch_bounds__(256) void k_csr(const unsigned* __restrict__ ebuf,
                                             const int* __restrict__ bbase,
                                             const int* __restrict__ bhist,
                                             int* __restrict__ off,
                                             float* __restrict__ invd,
                                             int* __restrict__ srcs, int N) {
  __shared__ int dcount[128];
  __shared__ int dloc[128];
  int b = blockIdx.x;
  int t = threadIdx.x;
  int beg = bbase[b];
  int end = beg + bhist[b];
  if (t < 128) dcount[t] = 0;
  __syncthreads();
  for (int i = beg + t; i < end; i += 256) atomicAdd(&dcount[ebuf[i] & 127], 1);
  __syncthreads();
  if (t < 128) dloc[t] = dcount[t];
  __syncthreads();
  for (int d = 1; d < 128; d <<= 1) {
    int x = 0, a = 0;
    if (t < 128) {
      x = dloc[t];
      if (t >= d) a = dloc[t - d];
    }
    __syncthreads();
    if (t < 128) dloc[t] = x + a;
    __syncthreads();
  }
  if (t < 128) {
    int node = b * 128 + t;
    if (node < N) {
      int ex = beg + dloc[t] - dcount[t];
      off[node] = ex;
      int c = dcount[t];
      invd[node] = c > 0 ? 1.0f / (float)c : 0.0f;
      dcount[t] = ex;  // becomes cursor
    }
  }
  __syncthreads();
  for (int i = beg + t; i < end; i += 256) {
    unsigned p = ebuf[i];
    int slot = atomicAdd(&dcount[p & 127], 1);
    srcs[slot] = (int)(p >> 16);
  }
}

// ---- fp32 -> bf16 cast, 4 elems/thread ----
__global__ void k_cast(const float* __restrict__ x, ushort* __restrict__ xb, int total4) {
  int i = blockIdx.x * blockDim.x + threadIdx.x;
  if (i >= total4) return;
  float4 v = *reinterpret_cast<const float4*>(x + (size_t)i * 4);
  ushort4 o;
  o.x = f2bf(v.x); o.y = f2bf(v.y); o.z = f2bf(v.z); o.w = f2bf(v.w);
  *reinterpret_cast<ushort4*>(xb + (size_t)i * 4) = o;
}

// ---- pack all 3 layers' [Wl;Wr] into MFMA B-fragment order, bf16 ----
// Per layer: element idx = ((kk*8+ct)*64 + lane)*8 + j holds
//   B[kk*32+(lane>>4)*8+j][ct*16+(lane&15)]   (B = [Wl;Wr], K=256 x 128)
__global__ void k_pack3(const float* __restrict__ Wl1, const float* __restrict__ Wr1,
                        const float* __restrict__ Wl2, const float* __restrict__ Wr2,
                        const float* __restrict__ Wl3, const float* __restrict__ Wr3,
                        ushort* __restrict__ Bp) {
  int gidx = blockIdx.x * blockDim.x + threadIdx.x;  // 3*32768 total
  int layer = gidx >> 15;
  int idx = gidx & 32767;
  const float* Wl = (layer == 0) ? Wl1 : (layer == 1) ? Wl2 : Wl3;
  const float* Wr = (layer == 0) ? Wr1 : (layer == 1) ? Wr2 : Wr3;
  int kk = idx >> 12;
  int ct = (idx >> 9) & 7;
  int l  = (idx >> 3) & 63;
  int j  = idx & 7;
  int k = kk * 32 + ((l >> 4) << 3) + j;
  int col = ct * 16 + (l & 15);
  float v = (k < 128) ? Wl[k * 128 + col] : Wr[(k - 128) * 128 + col];
  Bp[gidx] = f2bf(v);
}

// ---- gather-mean: ONE WAVE PER NODE ----
// Lane owns 2 features (ushort2, 4B) -> 64 lanes read one 256B row coalesced
// per edge. Edge indices fetched 64-at-a-time coalesced, shfl-broadcast.
// Row reads unrolled x4 -> 4 independent loads in flight per wave.
__global__ __launch_bounds__(256) void k_gather(const ushort* __restrict__ hin,
                                                const int* __restrict__ off,
                                                const int* __restrict__ srcs,
                                                const float* __restrict__ invd,
                                                ushort* __restrict__ meanb, int N) {
  int wid = blockIdx.x * 4 + (threadIdx.x >> 6);  // node = global wave id
  if (wid >= N) return;
  int lane = threadIdx.x & 63;
  int lo = off[wid], hi = off[wid + 1];
  float a0 = 0.f, a1 = 0.f;

  for (int base = lo; base < hi; base += 64) {
    int cnt = min(64, hi - base);
    int myidx = (base + lane < hi) ? srcs[base + lane] : 0;
    int j = 0;
    for (; j + 3 < cnt; j += 4) {
      int s0 = __shfl(myidx, j);
      int s1 = __shfl(myidx, j + 1);
      int s2 = __shfl(myidx, j + 2);
      int s3 = __shfl(myidx, j + 3);
      ushort2 v0 = *reinterpret_cast<const ushort2*>(hin + (size_t)s0 * D + lane * 2);
      ushort2 v1 = *reinterpret_cast<const ushort2*>(hin + (size_t)s1 * D + lane * 2);
      ushort2 v2 = *reinterpret_cast<const ushort2*>(hin + (size_t)s2 * D + lane * 2);
      ushort2 v3 = *reinterpret_cast<const ushort2*>(hin + (size_t)s3 * D + lane * 2);
      a0 += bf2f(v0.x); a1 += bf2f(v0.y);
      a0 += bf2f(v1.x); a1 += bf2f(v1.y);
      a0 += bf2f(v2.x); a1 += bf2f(v2.y);
      a0 += bf2f(v3.x); a1 += bf2f(v3.y);
    }
    for (; j < cnt; ++j) {
      int s = __shfl(myidx, j);
      ushort2 v = *reinterpret_cast<const ushort2*>(hin + (size_t)s * D + lane * 2);
      a0 += bf2f(v.x); a1 += bf2f(v.y);
    }
  }
  float w = invd[wid];
  ushort2 o;
  o.x = f2bf(a0 * w);
  o.y = f2bf(a1 * w);
  *reinterpret_cast<ushort2*>(meanb + (size_t)wid * D + lane * 2) = o;
}

// ---- MFMA combine: block = 256 thr = 4 waves; wave w owns rows [row0+w*16,+16) ----
// A-frag: lane holds A[row0+w*16+(l&15)][kk*32+(l>>4)*8 + 0..7] (16B global load).
// B-frag: pre-packed, lane loads 16B at ((kk*8+ct)*64+l)*8.
// C/D: row=(l>>4)*4+reg, col=ct*16+(l&15)  [m89-verified layout]
template <int RELU, int FINAL>
__global__ __launch_bounds__(256) void k_combine(const ushort* __restrict__ meanb,
                                                 const ushort* __restrict__ hb,
                                                 const ushort* __restrict__ Bpack,
                                                 const float* __restrict__ bias,
                                                 float* __restrict__ outf,
                                                 ushort* __restrict__ outh, int N) {
  int l = threadIdx.x & 63;
  int w = threadIdx.x >> 6;
  int row0 = blockIdx.x * 64 + w * 16;
  int lr = l & 15;
  int kgrp = l >> 4;
  int arow = row0 + lr;
  if (arow >= N) arow = N - 1;  // clamp loads; stores guarded
  size_t abase = (size_t)arow * D;

  f32x4 acc[8];
#pragma unroll
  for (int ct = 0; ct < 8; ++ct) {
    float bv = bias[ct * 16 + lr];
    acc[ct] = (f32x4){bv, bv, bv, bv};
  }

#pragma unroll
  for (int kk = 0; kk < 8; ++kk) {
    const ushort* asrc = (kk < 4) ? meanb : hb;
    int klocal = ((kk & 3) << 5) + (kgrp << 3);
    bf16x8 a = *reinterpret_cast<const bf16x8*>(asrc + abase + klocal);
    const ushort* bb = Bpack + ((size_t)kk << 12) + ((size_t)l << 3);
#pragma unroll
    for (int ct = 0; ct < 8; ++ct) {
      bf16x8 b = *reinterpret_cast<const bf16x8*>(bb + (ct << 9));
      acc[ct] = __builtin_amdgcn_mfma_f32_16x16x32_bf16(a, b, acc[ct], 0, 0, 0);
    }
  }

#pragma unroll
  for (int ct = 0; ct < 8; ++ct) {
    int c = ct * 16 + lr;
#pragma unroll
    for (int r = 0; r < 4; ++r) {
      int rr = row0 + kgrp * 4 + r;
      if (rr < N) {
        float v = acc[ct][r];
        if (RELU) v = fmaxf(v, 0.f);
        if (FINAL) outf[(size_t)rr * D + c] = v;
        else outh[(size_t)rr * D + c] = f2bf(v);
      }
    }
  }
}

extern "C" void kernel_launch(void* const* d_in, const int* in_sizes, int n_in,
                              void* d_out, int out_size, void* d_ws, size_t ws_size,
                              hipStream_t stream) {
  const float* x   = (const float*)d_in[0];
  const int*   ei  = (const int*)d_in[1];
  const float* Wl1 = (const float*)d_in[2];
  const float* b1  = (const float*)d_in[3];
  const float* Wr1 = (const float*)d_in[4];
  const float* Wl2 = (const float*)d_in[5];
  const float* b2  = (const float*)d_in[6];
  const float* Wr2 = (const float*)d_in[7];
  const float* Wl3 = (const float*)d_in[8];
  const float* b3  = (const float*)d_in[9];
  const float* Wr3 = (const float*)d_in[10];
  float* out = (float*)d_out;

  int N = in_sizes[0] / D;
  int E = in_sizes[1] / 2;
  const int* srcp = ei;
  const int* dstp = ei + E;
  int NB = (N + 127) >> 7;  // 391 for N=50000

  char* p = (char*)d_ws;
  auto carve = [&](size_t bytes) {
    void* r = (void*)p;
    p += (bytes + 255) & ~(size_t)255;
    return r;
  };
  int*      bhist = (int*)carve((size_t)512 * 4);
  int*      bbase = (int*)carve((size_t)512 * 4);
  int*      bcur  = (int*)carve((size_t)512 * 4);
  int*      off   = (int*)carve((size_t)(N + 1) * 4);
  float*    invd  = (float*)carve((size_t)N * 4);
  int*      srcs  = (int*)carve((size_t)E * 4);
  unsigned* ebuf  = (unsigned*)carve((size_t)E * 4);
  ushort*   xb    = (ushort*)carve((size_t)N * D * 2);
  ushort*   h1b   = (ushort*)carve((size_t)N * D * 2);
  ushort*   h2b   = (ushort*)carve((size_t)N * D * 2);
  ushort*   meanb = (ushort*)carve((size_t)N * D * 2);
  ushort*   Bp    = (ushort*)carve((size_t)3 * 32768 * 2);

  // --- CSR build (bucketed) ---
  hipMemsetAsync(bhist, 0, (size_t)NB * 4, stream);
  int ch_blocks = (E + 4095) / 4096;
  k_bhist<<<ch_blocks, 256, 0, stream>>>(dstp, bhist, E, NB);
  k_bscan<<<1, 512, 0, stream>>>(bhist, bbase, bcur, off + N, NB);
  k_bucket<<<ch_blocks, 256, 0, stream>>>(srcp, dstp, bcur, ebuf, E, NB);
  k_csr<<<NB, 256, 0, stream>>>(ebuf, bbase, bhist, off, invd, srcs, N);

  // --- casts + weight packing ---
  int total4 = N * D / 4;
  k_cast<<<(total4 + 255) / 256, 256, 0, stream>>>(x, xb, total4);
  k_pack3<<<3 * 32768 / 256, 256, 0, stream>>>(Wl1, Wr1, Wl2, Wr2, Wl3, Wr3, Bp);

  int gather_blocks  = (N + 3) / 4;         // 1 wave per node, 4 waves per block
  int combine_blocks = (N + 63) / 64;

  // --- layer 1: xb -> h1b (relu) ---
  k_gather<<<gather_blocks, 256, 0, stream>>>(xb, off, srcs, invd, meanb, N);
  k_combine<1, 0><<<combine_blocks, 256, 0, stream>>>(meanb, xb, Bp, b1, nullptr, h1b, N);
  // --- layer 2: h1b -> h2b (relu) ---
  k_gather<<<gather_blocks, 256, 0, stream>>>(h1b, off, srcs, invd, meanb, N);
  k_combine<1, 0><<<combine_blocks, 256, 0, stream>>>(meanb, h1b, Bp + 32768, b2, nullptr, h2b, N);
  // --- layer 3: h2b -> out (fp32, no relu) ---
  k_gather<<<gather_blocks, 256, 0, stream>>>(h2b, off, srcs, invd, meanb, N);
  k_combine<0, 1><<<combine_blocks, 256, 0, stream>>>(meanb, h2b, Bp + 2 * 32768, b3, out, nullptr, N);
}

// Round 7
// 197.595 us; speedup vs baseline: 1.3831x; 1.0072x over previous
//
#include <hip/hip_runtime.h>

// GraphSAGE 3-layer forward.
// CSR build via 2-level bucketing (dst>>7 buckets of 128 nodes):
//   k_bhist -> k_bscan -> k_bucket (packed (src<<16|dst) into bucket regions)
//   -> k_csr (per-bucket per-dst scan -> off/invd/srcs).
// Feature pipeline (bf16): cast x once; per layer:
//   k_gather (R7: wave per node, 16 lanes x 16B per edge-row -> 4 edges per
//             step, unroll x2 = 8 outstanding 16B loads; shfl_xor reduce.
//             R6 was 4B/lane + shfl-broadcast = issue/latency-bound)
//   k_combine (MFMA mfma_f32_16x16x32_bf16, weights pre-packed in frag order).
// N=50000, E=800000, D=128, K=256. Requires N <= 65536 (16-bit edge packing).

#define D 128

typedef __attribute__((ext_vector_type(8))) short bf16x8;
typedef __attribute__((ext_vector_type(4))) float f32x4;

__device__ inline ushort f2bf(float f) {
  union { float f; unsigned u; } v; v.f = f;
  unsigned r = v.u + 0x7fffu + ((v.u >> 16) & 1u);
  return (ushort)(r >> 16);
}
__device__ inline float bf2f(ushort h) {
  union { unsigned u; float f; } v; v.u = ((unsigned)h) << 16;
  return v.f;
}

// ---- CSR stage 1: global bucket histogram (LDS-aggregated) ----
__global__ __launch_bounds__(256) void k_bhist(const int* __restrict__ dst,
                                               int* __restrict__ bhist, int E, int NB) {
  __shared__ int h[512];
  int t = threadIdx.x;
  for (int i = t; i < NB; i += 256) h[i] = 0;
  __syncthreads();
  int beg = blockIdx.x * 4096;
  int end = min(beg + 4096, E);
  for (int i = beg + t; i < end; i += 256) atomicAdd(&h[dst[i] >> 7], 1);
  __syncthreads();
  for (int i = t; i < NB; i += 256)
    if (h[i]) atomicAdd(&bhist[i], h[i]);
}

// ---- CSR stage 2: scan bucket counts -> bases; init cursors; off[N]=E ----
__global__ __launch_bounds__(512) void k_bscan(const int* __restrict__ bhist,
                                               int* __restrict__ bbase,
                                               int* __restrict__ bcur,
                                               int* __restrict__ offN, int NB) {
  __shared__ int part[512];
  int t = threadIdx.x;
  part[t] = (t < NB) ? bhist[t] : 0;
  __syncthreads();
  for (int d = 1; d < 512; d <<= 1) {
    int x = part[t];
    int a = (t >= d) ? part[t - d] : 0;
    __syncthreads();
    part[t] = x + a;
    __syncthreads();
  }
  if (t < NB) {
    int b = (t == 0) ? 0 : part[t - 1];
    bbase[t] = b;
    bcur[t] = b;
  }
  if (t == NB - 1) *offN = part[t];
}

// ---- CSR stage 3: partition edges into bucket regions (packed u32) ----
__global__ __launch_bounds__(256) void k_bucket(const int* __restrict__ src,
                                                const int* __restrict__ dst,
                                                int* __restrict__ bcur,
                                                unsigned* __restrict__ ebuf,
                                                int E, int NB) {
  __shared__ int h[512];
  __shared__ int base[512];
  int t = threadIdx.x;
  for (int i = t; i < NB; i += 256) h[i] = 0;
  __syncthreads();
  int beg = blockIdx.x * 4096;
  int end = min(beg + 4096, E);
  for (int i = beg + t; i < end; i += 256) atomicAdd(&h[dst[i] >> 7], 1);
  __syncthreads();
  for (int i = t; i < NB; i += 256) {
    int c = h[i];
    base[i] = c ? atomicAdd(&bcur[i], c) : 0;
    h[i] = 0;
  }
  __syncthreads();
  for (int i = beg + t; i < end; i += 256) {
    int d = dst[i];
    int b = d >> 7;
    int r = atomicAdd(&h[b], 1);
    ebuf[base[b] + r] = (((unsigned)src[i]) << 16) | (unsigned)d;
  }
}

// ---- CSR stage 4: per-bucket per-dst CSR (one block per bucket) ----
__global__ __launch_bounds__(256) void k_csr(const unsigned* __restrict__ ebuf,
                                             const int* __restrict__ bbase,
                                             const int* __restrict__ bhist,
                                             int* __restrict__ off,
                                             float* __restrict__ invd,
                                             int* __restrict__ srcs, int N) {
  __shared__ int dcount[128];
  __shared__ int dloc[128];
  int b = blockIdx.x;
  int t = threadIdx.x;
  int beg = bbase[b];
  int end = beg + bhist[b];
  if (t < 128) dcount[t] = 0;
  __syncthreads();
  for (int i = beg + t; i < end; i += 256) atomicAdd(&dcount[ebuf[i] & 127], 1);
  __syncthreads();
  if (t < 128) dloc[t] = dcount[t];
  __syncthreads();
  for (int d = 1; d < 128; d <<= 1) {
    int x = 0, a = 0;
    if (t < 128) {
      x = dloc[t];
      if (t >= d) a = dloc[t - d];
    }
    __syncthreads();
    if (t < 128) dloc[t] = x + a;
    __syncthreads();
  }
  if (t < 128) {
    int node = b * 128 + t;
    if (node < N) {
      int ex = beg + dloc[t] - dcount[t];
      off[node] = ex;
      int c = dcount[t];
      invd[node] = c > 0 ? 1.0f / (float)c : 0.0f;
      dcount[t] = ex;  // becomes cursor
    }
  }
  __syncthreads();
  for (int i = beg + t; i < end; i += 256) {
    unsigned p = ebuf[i];
    int slot = atomicAdd(&dcount[p & 127], 1);
    srcs[slot] = (int)(p >> 16);
  }
}

// ---- fp32 -> bf16 cast, 4 elems/thread ----
__global__ void k_cast(const float* __restrict__ x, ushort* __restrict__ xb, int total4) {
  int i = blockIdx.x * blockDim.x + threadIdx.x;
  if (i >= total4) return;
  float4 v = *reinterpret_cast<const float4*>(x + (size_t)i * 4);
  ushort4 o;
  o.x = f2bf(v.x); o.y = f2bf(v.y); o.z = f2bf(v.z); o.w = f2bf(v.w);
  *reinterpret_cast<ushort4*>(xb + (size_t)i * 4) = o;
}

// ---- pack all 3 layers' [Wl;Wr] into MFMA B-fragment order, bf16 ----
// Per layer: element idx = ((kk*8+ct)*64 + lane)*8 + j holds
//   B[kk*32+(lane>>4)*8+j][ct*16+(lane&15)]   (B = [Wl;Wr], K=256 x 128)
__global__ void k_pack3(const float* __restrict__ Wl1, const float* __restrict__ Wr1,
                        const float* __restrict__ Wl2, const float* __restrict__ Wr2,
                        const float* __restrict__ Wl3, const float* __restrict__ Wr3,
                        ushort* __restrict__ Bp) {
  int gidx = blockIdx.x * blockDim.x + threadIdx.x;  // 3*32768 total
  int layer = gidx >> 15;
  int idx = gidx & 32767;
  const float* Wl = (layer == 0) ? Wl1 : (layer == 1) ? Wl2 : Wl3;
  const float* Wr = (layer == 0) ? Wr1 : (layer == 1) ? Wr2 : Wr3;
  int kk = idx >> 12;
  int ct = (idx >> 9) & 7;
  int l  = (idx >> 3) & 63;
  int j  = idx & 7;
  int k = kk * 32 + ((l >> 4) << 3) + j;
  int col = ct * 16 + (l & 15);
  float v = (k < 128) ? Wl[k * 128 + col] : Wr[(k - 128) * 128 + col];
  Bp[gidx] = f2bf(v);
}

// ---- gather-mean: one wave per node, 16 lanes x 16B per edge-row ----
// lane = (g,s): g = edge slot (4 edges in flight), s = feature octet.
// Per step the wave reads 4 full 256B rows; unroll x2 -> 8 outstanding loads.
// Cross-group sum via shfl_xor(16,32); lanes 0-15 write the 256B mean row.
__global__ __launch_bounds__(256) void k_gather(const ushort* __restrict__ hin,
                                                const int* __restrict__ off,
                                                const int* __restrict__ srcs,
                                                const float* __restrict__ invd,
                                                ushort* __restrict__ meanb, int N) {
  int wid = blockIdx.x * 4 + (threadIdx.x >> 6);  // node = global wave id
  if (wid >= N) return;
  int lane = threadIdx.x & 63;
  int g = lane >> 4;   // edge slot 0..3
  int s = lane & 15;   // feature octet: features [s*8, s*8+8)
  int lo = off[wid], hi = off[wid + 1];

  float acc[8] = {0.f, 0.f, 0.f, 0.f, 0.f, 0.f, 0.f, 0.f};
  int e = lo + g;
  for (; e + 4 < hi; e += 8) {
    int i0 = srcs[e];
    int i1 = srcs[e + 4];
    bf16x8 v0 = *reinterpret_cast<const bf16x8*>(hin + (size_t)i0 * D + s * 8);
    bf16x8 v1 = *reinterpret_cast<const bf16x8*>(hin + (size_t)i1 * D + s * 8);
#pragma unroll
    for (int j = 0; j < 8; ++j) acc[j] += bf2f((ushort)v0[j]);
#pragma unroll
    for (int j = 0; j < 8; ++j) acc[j] += bf2f((ushort)v1[j]);
  }
  if (e < hi) {
    int i0 = srcs[e];
    bf16x8 v0 = *reinterpret_cast<const bf16x8*>(hin + (size_t)i0 * D + s * 8);
#pragma unroll
    for (int j = 0; j < 8; ++j) acc[j] += bf2f((ushort)v0[j]);
  }

#pragma unroll
  for (int j = 0; j < 8; ++j) acc[j] += __shfl_xor(acc[j], 16);
#pragma unroll
  for (int j = 0; j < 8; ++j) acc[j] += __shfl_xor(acc[j], 32);

  if (lane < 16) {
    float w = invd[wid];
    bf16x8 o;
#pragma unroll
    for (int j = 0; j < 8; ++j) o[j] = (short)f2bf(acc[j] * w);
    *reinterpret_cast<bf16x8*>(meanb + (size_t)wid * D + s * 8) = o;
  }
}

// ---- MFMA combine: block = 256 thr = 4 waves; wave w owns rows [row0+w*16,+16) ----
// A-frag: lane holds A[row0+w*16+(l&15)][kk*32+(l>>4)*8 + 0..7] (16B global load).
// B-frag: pre-packed, lane loads 16B at ((kk*8+ct)*64+l)*8.
// C/D: row=(l>>4)*4+reg, col=ct*16+(l&15)  [m89-verified layout]
template <int RELU, int FINAL>
__global__ __launch_bounds__(256) void k_combine(const ushort* __restrict__ meanb,
                                                 const ushort* __restrict__ hb,
                                                 const ushort* __restrict__ Bpack,
                                                 const float* __restrict__ bias,
                                                 float* __restrict__ outf,
                                                 ushort* __restrict__ outh, int N) {
  int l = threadIdx.x & 63;
  int w = threadIdx.x >> 6;
  int row0 = blockIdx.x * 64 + w * 16;
  int lr = l & 15;
  int kgrp = l >> 4;
  int arow = row0 + lr;
  if (arow >= N) arow = N - 1;  // clamp loads; stores guarded
  size_t abase = (size_t)arow * D;

  f32x4 acc[8];
#pragma unroll
  for (int ct = 0; ct < 8; ++ct) {
    float bv = bias[ct * 16 + lr];
    acc[ct] = (f32x4){bv, bv, bv, bv};
  }

#pragma unroll
  for (int kk = 0; kk < 8; ++kk) {
    const ushort* asrc = (kk < 4) ? meanb : hb;
    int klocal = ((kk & 3) << 5) + (kgrp << 3);
    bf16x8 a = *reinterpret_cast<const bf16x8*>(asrc + abase + klocal);
    const ushort* bb = Bpack + ((size_t)kk << 12) + ((size_t)l << 3);
#pragma unroll
    for (int ct = 0; ct < 8; ++ct) {
      bf16x8 b = *reinterpret_cast<const bf16x8*>(bb + (ct << 9));
      acc[ct] = __builtin_amdgcn_mfma_f32_16x16x32_bf16(a, b, acc[ct], 0, 0, 0);
    }
  }

#pragma unroll
  for (int ct = 0; ct < 8; ++ct) {
    int c = ct * 16 + lr;
#pragma unroll
    for (int r = 0; r < 4; ++r) {
      int rr = row0 + kgrp * 4 + r;
      if (rr < N) {
        float v = acc[ct][r];
        if (RELU) v = fmaxf(v, 0.f);
        if (FINAL) outf[(size_t)rr * D + c] = v;
        else outh[(size_t)rr * D + c] = f2bf(v);
      }
    }
  }
}

extern "C" void kernel_launch(void* const* d_in, const int* in_sizes, int n_in,
                              void* d_out, int out_size, void* d_ws, size_t ws_size,
                              hipStream_t stream) {
  const float* x   = (const float*)d_in[0];
  const int*   ei  = (const int*)d_in[1];
  const float* Wl1 = (const float*)d_in[2];
  const float* b1  = (const float*)d_in[3];
  const float* Wr1 = (const float*)d_in[4];
  const float* Wl2 = (const float*)d_in[5];
  const float* b2  = (const float*)d_in[6];
  const float* Wr2 = (const float*)d_in[7];
  const float* Wl3 = (const float*)d_in[8];
  const float* b3  = (const float*)d_in[9];
  const float* Wr3 = (const float*)d_in[10];
  float* out = (float*)d_out;

  int N = in_sizes[0] / D;
  int E = in_sizes[1] / 2;
  const int* srcp = ei;
  const int* dstp = ei + E;
  int NB = (N + 127) >> 7;  // 391 for N=50000

  char* p = (char*)d_ws;
  auto carve = [&](size_t bytes) {
    void* r = (void*)p;
    p += (bytes + 255) & ~(size_t)255;
    return r;
  };
  int*      bhist = (int*)carve((size_t)512 * 4);
  int*      bbase = (int*)carve((size_t)512 * 4);
  int*      bcur  = (int*)carve((size_t)512 * 4);
  int*      off   = (int*)carve((size_t)(N + 1) * 4);
  float*    invd  = (float*)carve((size_t)N * 4);
  int*      srcs  = (int*)carve((size_t)E * 4);
  unsigned* ebuf  = (unsigned*)carve((size_t)E * 4);
  ushort*   xb    = (ushort*)carve((size_t)N * D * 2);
  ushort*   h1b   = (ushort*)carve((size_t)N * D * 2);
  ushort*   h2b   = (ushort*)carve((size_t)N * D * 2);
  ushort*   meanb = (ushort*)carve((size_t)N * D * 2);
  ushort*   Bp    = (ushort*)carve((size_t)3 * 32768 * 2);

  // --- CSR build (bucketed) ---
  hipMemsetAsync(bhist, 0, (size_t)NB * 4, stream);
  int ch_blocks = (E + 4095) / 4096;
  k_bhist<<<ch_blocks, 256, 0, stream>>>(dstp, bhist, E, NB);
  k_bscan<<<1, 512, 0, stream>>>(bhist, bbase, bcur, off + N, NB);
  k_bucket<<<ch_blocks, 256, 0, stream>>>(srcp, dstp, bcur, ebuf, E, NB);
  k_csr<<<NB, 256, 0, stream>>>(ebuf, bbase, bhist, off, invd, srcs, N);

  // --- casts + weight packing ---
  int total4 = N * D / 4;
  k_cast<<<(total4 + 255) / 256, 256, 0, stream>>>(x, xb, total4);
  k_pack3<<<3 * 32768 / 256, 256, 0, stream>>>(Wl1, Wr1, Wl2, Wr2, Wl3, Wr3, Bp);

  int gather_blocks  = (N + 3) / 4;         // 1 wave per node, 4 waves per block
  int combine_blocks = (N + 63) / 64;

  // --- layer 1: xb -> h1b (relu) ---
  k_gather<<<gather_blocks, 256, 0, stream>>>(xb, off, srcs, invd, meanb, N);
  k_combine<1, 0><<<combine_blocks, 256, 0, stream>>>(meanb, xb, Bp, b1, nullptr, h1b, N);
  // --- layer 2: h1b -> h2b (relu) ---
  k_gather<<<gather_blocks, 256, 0, stream>>>(h1b, off, srcs, invd, meanb, N);
  k_combine<1, 0><<<combine_blocks, 256, 0, stream>>>(meanb, h1b, Bp + 32768, b2, nullptr, h2b, N);
  // --- layer 3: h2b -> out (fp32, no relu) ---
  k_gather<<<gather_blocks, 256, 0, stream>>>(h2b, off, srcs, invd, meanb, N);
  k_combine<0, 1><<<combine_blocks, 256, 0, stream>>>(meanb, h2b, Bp + 2 * 32768, b3, out, nullptr, N);
}

// Round 8
// 180.621 us; speedup vs baseline: 1.5131x; 1.0940x over previous
//
#include <hip/hip_runtime.h>

// GraphSAGE 3-layer forward.
// CSR build via 2-level bucketing (dst>>7 buckets of 128 nodes):
//   k_bhist -> k_bscan -> k_bucket (packed (src<<16|dst) into bucket regions)
//   -> k_csr (per-bucket per-dst scan -> off/invd/srcs).
// Feature pipeline (bf16): cast x once; per layer ONE fused kernel (R8):
//   k_fused: 16-node blocks (3125 blocks -> 12.5k waves, full TLP; R5's 64-node
//   fusion starved at 12 waves/CU). Phase 1: each of 4 waves gathers 4 nodes
//   serially (16 lanes x 16B per edge row, shfl_xor reduce) -> 4KB XOR-swizzled
//   LDS mean tile. Phase 2: MFMA 16x128 tile, wave w owns cols [w*32,w*32+32);
//   A from LDS(mean)/global(h), B pre-packed in fragment order. Combine's
//   MFMA+traffic hides under gather's BW-bound phase; meanb round-trip gone.
// N=50000, E=800000, D=128, K=256. Requires N <= 65536 (16-bit edge packing).

#define D 128

typedef __attribute__((ext_vector_type(8))) short bf16x8;
typedef __attribute__((ext_vector_type(4))) float f32x4;

__device__ inline ushort f2bf(float f) {
  union { float f; unsigned u; } v; v.f = f;
  unsigned r = v.u + 0x7fffu + ((v.u >> 16) & 1u);
  return (ushort)(r >> 16);
}
__device__ inline float bf2f(ushort h) {
  union { unsigned u; float f; } v; v.u = ((unsigned)h) << 16;
  return v.f;
}

// ---- CSR stage 1: global bucket histogram (LDS-aggregated) ----
__global__ __launch_bounds__(256) void k_bhist(const int* __restrict__ dst,
                                               int* __restrict__ bhist, int E, int NB) {
  __shared__ int h[512];
  int t = threadIdx.x;
  for (int i = t; i < NB; i += 256) h[i] = 0;
  __syncthreads();
  int beg = blockIdx.x * 4096;
  int end = min(beg + 4096, E);
  for (int i = beg + t; i < end; i += 256) atomicAdd(&h[dst[i] >> 7], 1);
  __syncthreads();
  for (int i = t; i < NB; i += 256)
    if (h[i]) atomicAdd(&bhist[i], h[i]);
}

// ---- CSR stage 2: scan bucket counts -> bases; init cursors; off[N]=E ----
__global__ __launch_bounds__(512) void k_bscan(const int* __restrict__ bhist,
                                               int* __restrict__ bbase,
                                               int* __restrict__ bcur,
                                               int* __restrict__ offN, int NB) {
  __shared__ int part[512];
  int t = threadIdx.x;
  part[t] = (t < NB) ? bhist[t] : 0;
  __syncthreads();
  for (int d = 1; d < 512; d <<= 1) {
    int x = part[t];
    int a = (t >= d) ? part[t - d] : 0;
    __syncthreads();
    part[t] = x + a;
    __syncthreads();
  }
  if (t < NB) {
    int b = (t == 0) ? 0 : part[t - 1];
    bbase[t] = b;
    bcur[t] = b;
  }
  if (t == NB - 1) *offN = part[t];
}

// ---- CSR stage 3: partition edges into bucket regions (packed u32) ----
__global__ __launch_bounds__(256) void k_bucket(const int* __restrict__ src,
                                                const int* __restrict__ dst,
                                                int* __restrict__ bcur,
                                                unsigned* __restrict__ ebuf,
                                                int E, int NB) {
  __shared__ int h[512];
  __shared__ int base[512];
  int t = threadIdx.x;
  for (int i = t; i < NB; i += 256) h[i] = 0;
  __syncthreads();
  int beg = blockIdx.x * 4096;
  int end = min(beg + 4096, E);
  for (int i = beg + t; i < end; i += 256) atomicAdd(&h[dst[i] >> 7], 1);
  __syncthreads();
  for (int i = t; i < NB; i += 256) {
    int c = h[i];
    base[i] = c ? atomicAdd(&bcur[i], c) : 0;
    h[i] = 0;
  }
  __syncthreads();
  for (int i = beg + t; i < end; i += 256) {
    int d = dst[i];
    int b = d >> 7;
    int r = atomicAdd(&h[b], 1);
    ebuf[base[b] + r] = (((unsigned)src[i]) << 16) | (unsigned)d;
  }
}

// ---- CSR stage 4: per-bucket per-dst CSR (one block per bucket) ----
__global__ __launch_bounds__(256) void k_csr(const unsigned* __restrict__ ebuf,
                                             const int* __restrict__ bbase,
                                             const int* __restrict__ bhist,
                                             int* __restrict__ off,
                                             float* __restrict__ invd,
                                             int* __restrict__ srcs, int N) {
  __shared__ int dcount[128];
  __shared__ int dloc[128];
  int b = blockIdx.x;
  int t = threadIdx.x;
  int beg = bbase[b];
  int end = beg + bhist[b];
  if (t < 128) dcount[t] = 0;
  __syncthreads();
  for (int i = beg + t; i < end; i += 256) atomicAdd(&dcount[ebuf[i] & 127], 1);
  __syncthreads();
  if (t < 128) dloc[t] = dcount[t];
  __syncthreads();
  for (int d = 1; d < 128; d <<= 1) {
    int x = 0, a = 0;
    if (t < 128) {
      x = dloc[t];
      if (t >= d) a = dloc[t - d];
    }
    __syncthreads();
    if (t < 128) dloc[t] = x + a;
    __syncthreads();
  }
  if (t < 128) {
    int node = b * 128 + t;
    if (node < N) {
      int ex = beg + dloc[t] - dcount[t];
      off[node] = ex;
      int c = dcount[t];
      invd[node] = c > 0 ? 1.0f / (float)c : 0.0f;
      dcount[t] = ex;  // becomes cursor
    }
  }
  __syncthreads();
  for (int i = beg + t; i < end; i += 256) {
    unsigned p = ebuf[i];
    int slot = atomicAdd(&dcount[p & 127], 1);
    srcs[slot] = (int)(p >> 16);
  }
}

// ---- fp32 -> bf16 cast, 4 elems/thread ----
__global__ void k_cast(const float* __restrict__ x, ushort* __restrict__ xb, int total4) {
  int i = blockIdx.x * blockDim.x + threadIdx.x;
  if (i >= total4) return;
  float4 v = *reinterpret_cast<const float4*>(x + (size_t)i * 4);
  ushort4 o;
  o.x = f2bf(v.x); o.y = f2bf(v.y); o.z = f2bf(v.z); o.w = f2bf(v.w);
  *reinterpret_cast<ushort4*>(xb + (size_t)i * 4) = o;
}

// ---- pack all 3 layers' [Wl;Wr] into MFMA B-fragment order, bf16 ----
// Per layer: element idx = ((kk*8+ct)*64 + lane)*8 + j holds
//   B[kk*32+(lane>>4)*8+j][ct*16+(lane&15)]   (B = [Wl;Wr], K=256 x 128)
__global__ void k_pack3(const float* __restrict__ Wl1, const float* __restrict__ Wr1,
                        const float* __restrict__ Wl2, const float* __restrict__ Wr2,
                        const float* __restrict__ Wl3, const float* __restrict__ Wr3,
                        ushort* __restrict__ Bp) {
  int gidx = blockIdx.x * blockDim.x + threadIdx.x;  // 3*32768 total
  int layer = gidx >> 15;
  int idx = gidx & 32767;
  const float* Wl = (layer == 0) ? Wl1 : (layer == 1) ? Wl2 : Wl3;
  const float* Wr = (layer == 0) ? Wr1 : (layer == 1) ? Wr2 : Wr3;
  int kk = idx >> 12;
  int ct = (idx >> 9) & 7;
  int l  = (idx >> 3) & 63;
  int j  = idx & 7;
  int k = kk * 32 + ((l >> 4) << 3) + j;
  int col = ct * 16 + (l & 15);
  float v = (k < 128) ? Wl[k * 128 + col] : Wr[(k - 128) * 128 + col];
  Bp[gidx] = f2bf(v);
}

// ---- fused layer kernel: 16 nodes per block, 4 waves ----
// Phase 1: wave w gathers nodes node0+w*4..+3 serially; per node:
//   lane=(g,s): g=edge slot (4 edges in flight), s=feature octet (16B),
//   unroll x2 -> 8 outstanding loads; shfl_xor(16,32) reduce; lanes 0-15
//   write the bf16 mean row into LDS at byte nl*256 + (s*16 ^ ((nl&7)<<4)).
// Phase 2: MFMA. Wave w owns cols [w*32, w*32+32) (ct = 2w, 2w+1).
//   A-frag: lane holds A[node0+(l&15)][kk*32+(l>>4)*8+0..7]; kk<4 from LDS
//   (swizzled read, 2-way max), kk>=4 from global h row. B pre-packed.
//   C/D: row=(l>>4)*4+reg, col=ct*16+(l&15)  [m89-verified layout]
template <int RELU, int FINAL>
__global__ __launch_bounds__(256, 6) void k_fused(const ushort* __restrict__ hin,
                                                  const int* __restrict__ off,
                                                  const int* __restrict__ srcs,
                                                  const float* __restrict__ invd,
                                                  const ushort* __restrict__ Bpack,
                                                  const float* __restrict__ bias,
                                                  float* __restrict__ outf,
                                                  ushort* __restrict__ outh, int N) {
  __shared__ ushort smean[16 * D];  // 4KB, swizzled
  int t = threadIdx.x;
  int w = t >> 6;
  int lane = t & 63;
  int node0 = blockIdx.x * 16;
  int g = lane >> 4;   // edge slot 0..3
  int s = lane & 15;   // feature octet

  // --- phase 1: gather-mean for this wave's 4 nodes ---
  for (int q = 0; q < 4; ++q) {
    int nl = w * 4 + q;
    int n = node0 + nl;
    float acc[8] = {0.f, 0.f, 0.f, 0.f, 0.f, 0.f, 0.f, 0.f};
    float wgt = 0.f;
    if (n < N) {
      wgt = invd[n];
      int lo = off[n], hi = off[n + 1];
      int e = lo + g;
      for (; e + 4 < hi; e += 8) {
        int i0 = srcs[e];
        int i1 = srcs[e + 4];
        bf16x8 v0 = *reinterpret_cast<const bf16x8*>(hin + (size_t)i0 * D + s * 8);
        bf16x8 v1 = *reinterpret_cast<const bf16x8*>(hin + (size_t)i1 * D + s * 8);
#pragma unroll
        for (int j = 0; j < 8; ++j) acc[j] += bf2f((ushort)v0[j]);
#pragma unroll
        for (int j = 0; j < 8; ++j) acc[j] += bf2f((ushort)v1[j]);
      }
      if (e < hi) {
        int i0 = srcs[e];
        bf16x8 v0 = *reinterpret_cast<const bf16x8*>(hin + (size_t)i0 * D + s * 8);
#pragma unroll
        for (int j = 0; j < 8; ++j) acc[j] += bf2f((ushort)v0[j]);
      }
    }
#pragma unroll
    for (int j = 0; j < 8; ++j) acc[j] += __shfl_xor(acc[j], 16);
#pragma unroll
    for (int j = 0; j < 8; ++j) acc[j] += __shfl_xor(acc[j], 32);
    if (lane < 16) {
      bf16x8 o;
#pragma unroll
      for (int j = 0; j < 8; ++j) o[j] = (short)f2bf(acc[j] * wgt);
      int byte = nl * 256 + ((s * 16) ^ ((nl & 7) << 4));
      *reinterpret_cast<bf16x8*>(reinterpret_cast<char*>(smean) + byte) = o;
    }
  }
  __syncthreads();

  // --- phase 2: MFMA combine, wave w owns ct = 2w, 2w+1 ---
  int lr = lane & 15;
  int kgrp = lane >> 4;
  int arow = node0 + lr;
  if (arow >= N) arow = N - 1;  // clamp loads; stores guarded
  size_t abase = (size_t)arow * D;

  f32x4 acc2[2];
#pragma unroll
  for (int i = 0; i < 2; ++i) {
    float bv = bias[(w * 2 + i) * 16 + lr];
    acc2[i] = (f32x4){bv, bv, bv, bv};
  }

#pragma unroll
  for (int kk = 0; kk < 8; ++kk) {
    int klocal = ((kk & 3) << 5) + (kgrp << 3);
    bf16x8 a;
    if (kk < 4) {
      int byte = lr * 256 + ((klocal * 2) ^ ((lr & 7) << 4));
      a = *reinterpret_cast<const bf16x8*>(reinterpret_cast<const char*>(smean) + byte);
    } else {
      a = *reinterpret_cast<const bf16x8*>(hin + abase + klocal);
    }
#pragma unroll
    for (int i = 0; i < 2; ++i) {
      int ct = w * 2 + i;
      bf16x8 b = *reinterpret_cast<const bf16x8*>(Bpack + (((size_t)(kk * 8 + ct) * 64 + lane) << 3));
      acc2[i] = __builtin_amdgcn_mfma_f32_16x16x32_bf16(a, b, acc2[i], 0, 0, 0);
    }
  }

#pragma unroll
  for (int i = 0; i < 2; ++i) {
    int c = (w * 2 + i) * 16 + lr;
#pragma unroll
    for (int r = 0; r < 4; ++r) {
      int rr = node0 + kgrp * 4 + r;
      if (rr < N) {
        float v = acc2[i][r];
        if (RELU) v = fmaxf(v, 0.f);
        if (FINAL) outf[(size_t)rr * D + c] = v;
        else outh[(size_t)rr * D + c] = f2bf(v);
      }
    }
  }
}

extern "C" void kernel_launch(void* const* d_in, const int* in_sizes, int n_in,
                              void* d_out, int out_size, void* d_ws, size_t ws_size,
                              hipStream_t stream) {
  const float* x   = (const float*)d_in[0];
  const int*   ei  = (const int*)d_in[1];
  const float* Wl1 = (const float*)d_in[2];
  const float* b1  = (const float*)d_in[3];
  const float* Wr1 = (const float*)d_in[4];
  const float* Wl2 = (const float*)d_in[5];
  const float* b2  = (const float*)d_in[6];
  const float* Wr2 = (const float*)d_in[7];
  const float* Wl3 = (const float*)d_in[8];
  const float* b3  = (const float*)d_in[9];
  const float* Wr3 = (const float*)d_in[10];
  float* out = (float*)d_out;

  int N = in_sizes[0] / D;
  int E = in_sizes[1] / 2;
  const int* srcp = ei;
  const int* dstp = ei + E;
  int NB = (N + 127) >> 7;  // 391 for N=50000

  char* p = (char*)d_ws;
  auto carve = [&](size_t bytes) {
    void* r = (void*)p;
    p += (bytes + 255) & ~(size_t)255;
    return r;
  };
  int*      bhist = (int*)carve((size_t)512 * 4);
  int*      bbase = (int*)carve((size_t)512 * 4);
  int*      bcur  = (int*)carve((size_t)512 * 4);
  int*      off   = (int*)carve((size_t)(N + 1) * 4);
  float*    invd  = (float*)carve((size_t)N * 4);
  int*      srcs  = (int*)carve((size_t)E * 4);
  unsigned* ebuf  = (unsigned*)carve((size_t)E * 4);
  ushort*   xb    = (ushort*)carve((size_t)N * D * 2);
  ushort*   h1b   = (ushort*)carve((size_t)N * D * 2);
  ushort*   h2b   = (ushort*)carve((size_t)N * D * 2);
  ushort*   Bp    = (ushort*)carve((size_t)3 * 32768 * 2);

  // --- CSR build (bucketed) ---
  hipMemsetAsync(bhist, 0, (size_t)NB * 4, stream);
  int ch_blocks = (E + 4095) / 4096;
  k_bhist<<<ch_blocks, 256, 0, stream>>>(dstp, bhist, E, NB);
  k_bscan<<<1, 512, 0, stream>>>(bhist, bbase, bcur, off + N, NB);
  k_bucket<<<ch_blocks, 256, 0, stream>>>(srcp, dstp, bcur, ebuf, E, NB);
  k_csr<<<NB, 256, 0, stream>>>(ebuf, bbase, bhist, off, invd, srcs, N);

  // --- casts + weight packing ---
  int total4 = N * D / 4;
  k_cast<<<(total4 + 255) / 256, 256, 0, stream>>>(x, xb, total4);
  k_pack3<<<3 * 32768 / 256, 256, 0, stream>>>(Wl1, Wr1, Wl2, Wr2, Wl3, Wr3, Bp);

  int fused_blocks = (N + 15) / 16;  // 3125

  // --- fused layers ---
  k_fused<1, 0><<<fused_blocks, 256, 0, stream>>>(xb, off, srcs, invd, Bp, b1, nullptr, h1b, N);
  k_fused<1, 0><<<fused_blocks, 256, 0, stream>>>(h1b, off, srcs, invd, Bp + 32768, b2, nullptr, h2b, N);
  k_fused<0, 1><<<fused_blocks, 256, 0, stream>>>(h2b, off, srcs, invd, Bp + 2 * 32768, b3, out, nullptr, N);
}